// Round 1
// 750.548 us; speedup vs baseline: 1.0093x; 1.0093x over previous
//
#include <hip/hip_runtime.h>

#define HW 256
#define NF 32
#define TCOLS 8

// ---- monotone float<->uint encoding so atomicMax(uint) == float max ----
__device__ __forceinline__ unsigned enc(float f) {
  unsigned u = __float_as_uint(f);
  return u ^ (0x80000000u | (unsigned)((int)u >> 31));
}
__device__ __forceinline__ float dec(unsigned k) {
  unsigned b = (k & 0x80000000u) ? (k ^ 0x80000000u) : ~k;
  return __uint_as_float(b);
}

__device__ __forceinline__ float4 mk4(float a, float b, float c, float d) {
  float4 v; v.x = a; v.y = b; v.z = c; v.w = d; return v;
}

// one recurrence element: normalize gates, then
// h = (1-a-b-c)*x + a*h[k-1] + b*h[k] + c*h[k+1]
__device__ __forceinline__ float stepf(float a, float b, float c, float xm,
                                       float hm, float hc, float hp) {
  float s = fabsf(a) + fabsf(b) + fabsf(c) + 1e-7f;
  float inv = __builtin_amdgcn_rcpf(s);
  if (s < 1.0f) inv = 1.0f;
  a *= inv; b *= inv; c *= inv;
  float h = (1.0f - a - b - c) * xm;
  h = fmaf(a, hm, h);
  h = fmaf(b, hc, h);
  h = fmaf(c, hp, h);
  return h;
}

// ======================= fast path: per-direction ws buffers ================
// 512 single-wave blocks (64 threads):
//   blocks 0..255   = horizontal planes (dir 0 fwd / dir 1 rev), scan over W,
//                     lane owns rows 4l..4l+3, halo via shfl — NO barriers.
//   blocks 256..511 = vertical planes (dir 2 fwd / dir 3 rev), scan over H,
//                     lane owns cols 4l..4l+3, halo via shfl — NO barriers.

// one column step of the horizontal scan (jj is a literal 0..7)
#define COL_STEP(jj)                                                        \
  {                                                                         \
    const float4 A  = *(const float4*)&tl[0][jj][4 * lane];                 \
    const float4 Bv = *(const float4*)&tl[1][jj][4 * lane];                 \
    const float4 Cv = *(const float4*)&tl[2][jj][4 * lane];                 \
    const float4 X  = *(const float4*)&tl[3][jj][4 * lane];                 \
    float left = __shfl_up(hv.w, 1);                                        \
    if (lane == 0) left = 0.f;                                              \
    float right = __shfl_down(hv.x, 1);                                     \
    if (lane == 63) right = 0.f;                                            \
    float4 hn;                                                              \
    hn.x = stepf(A.x, Bv.x, Cv.x, X.x, left, hv.x, hv.y);                   \
    hn.y = stepf(A.y, Bv.y, Cv.y, X.y, hv.x, hv.y, hv.z);                   \
    hn.z = stepf(A.z, Bv.z, Cv.z, X.z, hv.y, hv.z, hv.w);                   \
    hn.w = stepf(A.w, Bv.w, Cv.w, X.w, hv.z, hv.w, right);                  \
    res[jj] = hn;                                                           \
    hv = hn;                                                                \
  }

__global__ __launch_bounds__(64, 1) void spn_scan_ws(
    const float* __restrict__ x, const float* __restrict__ mask,
    float* __restrict__ ws) {
  const int bid = blockIdx.x;
  const int lane = threadIdx.x;  // 0..63, one wave per block
  const size_t plane = (size_t)HW * HW;
  const size_t PBUF = (size_t)4 * NF * plane;  // one direction buffer

  if (bid < 256) {
    // ---------------- horizontal: scan w, cross dim = rows (h) -------------
    __shared__ float tl[4][TCOLS][HW];  // [plane][col][row], transposed tiles
    const int dir = bid >> 7;
    const int rem = bid & 127;
    const int b = rem >> 5, ch = rem & 31;
    const bool rev = (dir == 1);
    const float* g1p = x + ((size_t)b * 12 * NF + (3 * dir + 0) * NF + ch) * plane;
    const float* g2p = x + ((size_t)b * 12 * NF + (3 * dir + 1) * NF + ch) * plane;
    const float* g3p = x + ((size_t)b * 12 * NF + (3 * dir + 2) * NF + ch) * plane;
    const float* mp  = mask + ((size_t)b * NF + ch) * plane;
    float* wdir = ws + (size_t)dir * PBUF + ((size_t)b * NF + ch) * plane;
    const float* ps[4] = {g1p, g2p, g3p, mp};

    const int r_lo = lane >> 1;       // 0..31 (row within 32-row pass)
    const int c0 = (lane & 1) * 4;    // col chunk within tile: 0 or 4
    float4 Pr[32];                    // reg-staged tile (4 planes x 8 passes)
    float4 hv = mk4(0.f, 0.f, 0.f, 0.f);

    int t0 = rev ? (HW - TCOLS) : 0;
    // prologue: load first tile into registers
#pragma unroll
    for (int q = 0; q < 32; ++q) {
      const int p = q >> 3, pass = q & 7;
      Pr[q] = *(const float4*)(ps[p] + (size_t)(pass * 32 + r_lo) * HW + t0 + c0);
    }

    for (int k = 0; k < HW / TCOLS; ++k) {
      // regs -> LDS transposed. bank = row%32: lanes 2m,2m+1 share a bank
      // (2-way aliasing is free on CDNA4); reads below are contiguous-16B
      // b128 per lane -> conflict-free.
#pragma unroll
      for (int q = 0; q < 32; ++q) {
        const int p = q >> 3, pass = q & 7;
        const int r = pass * 32 + r_lo;
        tl[p][c0 + 0][r] = Pr[q].x;
        tl[p][c0 + 1][r] = Pr[q].y;
        tl[p][c0 + 2][r] = Pr[q].z;
        tl[p][c0 + 3][r] = Pr[q].w;
      }
      const int t0c = t0;
      t0 += rev ? -TCOLS : TCOLS;
      if (k + 1 < HW / TCOLS) {
        // prefetch next tile; issued before the fence, lands under compute.
        // (register WAR on Pr orders these after the ds_writes' reads.)
#pragma unroll
        for (int q = 0; q < 32; ++q) {
          const int p = q >> 3, pass = q & 7;
          Pr[q] = *(const float4*)(ps[p] + (size_t)(pass * 32 + r_lo) * HW + t0 + c0);
        }
      }
      // intra-wave LDS write->read ordering: DS pipe is in-order per wave;
      // the fence stops the compiler hoisting the tile reads above the writes
      // and guarantees completion. No s_barrier anywhere in this kernel.
      asm volatile("s_waitcnt lgkmcnt(0)" ::: "memory");

      float4 res[TCOLS];
      if (!rev) {
        COL_STEP(0) COL_STEP(1) COL_STEP(2) COL_STEP(3)
        COL_STEP(4) COL_STEP(5) COL_STEP(6) COL_STEP(7)
      } else {
        COL_STEP(7) COL_STEP(6) COL_STEP(5) COL_STEP(4)
        COL_STEP(3) COL_STEP(2) COL_STEP(1) COL_STEP(0)
      }

      // store: per owned row, 2x float4 (32B contiguous per row)
      float* wr = wdir + (size_t)(4 * lane) * HW + t0c;
      *(float4*)(wr)              = mk4(res[0].x, res[1].x, res[2].x, res[3].x);
      *(float4*)(wr + 4)          = mk4(res[4].x, res[5].x, res[6].x, res[7].x);
      *(float4*)(wr + HW)         = mk4(res[0].y, res[1].y, res[2].y, res[3].y);
      *(float4*)(wr + HW + 4)     = mk4(res[4].y, res[5].y, res[6].y, res[7].y);
      *(float4*)(wr + 2 * HW)     = mk4(res[0].z, res[1].z, res[2].z, res[3].z);
      *(float4*)(wr + 2 * HW + 4) = mk4(res[4].z, res[5].z, res[6].z, res[7].z);
      *(float4*)(wr + 3 * HW)     = mk4(res[0].w, res[1].w, res[2].w, res[3].w);
      *(float4*)(wr + 3 * HW + 4) = mk4(res[4].w, res[5].w, res[6].w, res[7].w);
    }
  } else {
    // ---------------- vertical: scan h, cross dim = cols (w) ---------------
    const int sid = bid - 256;  // 0..255
    const int dir = 2 + (sid >> 7);
    const int rem = sid & 127;
    const int b = rem >> 5, ch = rem & 31;
    const bool rev = (dir == 3);
    const float* g1p = x + ((size_t)b * 12 * NF + (3 * dir + 0) * NF + ch) * plane;
    const float* g2p = x + ((size_t)b * 12 * NF + (3 * dir + 1) * NF + ch) * plane;
    const float* g3p = x + ((size_t)b * 12 * NF + (3 * dir + 2) * NF + ch) * plane;
    const float* mp  = mask + ((size_t)b * NF + ch) * plane;
    float* wdir = ws + (size_t)dir * PBUF + ((size_t)b * NF + ch) * plane;

    const int koff = lane * 4;  // lane owns w = 4*lane .. 4*lane+3
    float4 hv = mk4(0.f, 0.f, 0.f, 0.f);
    float4 Ab[4], Bb[4], Cb[4], Xb[4];  // depth-4 prefetch ring
#pragma unroll
    for (int p = 0; p < 4; ++p) {
      const int t = rev ? (HW - 1 - p) : p;
      const size_t ro = (size_t)t * HW + koff;
      Ab[p] = *(const float4*)(g1p + ro);
      Bb[p] = *(const float4*)(g2p + ro);
      Cb[p] = *(const float4*)(g3p + ro);
      Xb[p] = *(const float4*)(mp + ro);
    }

#define VSTEP(s, ph)                                                        \
  {                                                                         \
    const int t = rev ? (HW - 1 - (s)) : (s);                               \
    const float4 A = Ab[ph], Bv = Bb[ph], Cv = Cb[ph], X = Xb[ph];          \
    float left = __shfl_up(hv.w, 1);                                        \
    if (lane == 0) left = 0.f;                                              \
    float right = __shfl_down(hv.x, 1);                                     \
    if (lane == 63) right = 0.f;                                            \
    float4 hn;                                                              \
    hn.x = stepf(A.x, Bv.x, Cv.x, X.x, left, hv.x, hv.y);                   \
    hn.y = stepf(A.y, Bv.y, Cv.y, X.y, hv.x, hv.y, hv.z);                   \
    hn.z = stepf(A.z, Bv.z, Cv.z, X.z, hv.y, hv.z, hv.w);                   \
    hn.w = stepf(A.w, Bv.w, Cv.w, X.w, hv.z, hv.w, right);                  \
    *(float4*)(wdir + (size_t)t * HW + koff) = hn;                          \
    const int sn = (s) + 4;                                                 \
    if (sn < HW) {                                                          \
      const int tn = rev ? (HW - 1 - sn) : sn;                              \
      const size_t ro = (size_t)tn * HW + koff;                             \
      Ab[ph] = *(const float4*)(g1p + ro);                                  \
      Bb[ph] = *(const float4*)(g2p + ro);                                  \
      Cb[ph] = *(const float4*)(g3p + ro);                                  \
      Xb[ph] = *(const float4*)(mp + ro);                                   \
    }                                                                       \
    hv = hn;                                                                \
  }

    for (int s = 0; s < HW; s += 4) {
      VSTEP(s + 0, 0);
      VSTEP(s + 1, 1);
      VSTEP(s + 2, 2);
      VSTEP(s + 3, 3);
    }
#undef VSTEP
  }
}

__global__ __launch_bounds__(256) void spn_combine(
    const float4* __restrict__ w0, const float4* __restrict__ w1,
    const float4* __restrict__ w2, const float4* __restrict__ w3,
    float4* __restrict__ o) {
  const int i = blockIdx.x * 256 + threadIdx.x;
  const float4 a = w0[i], b = w1[i], c = w2[i], d = w3[i];
  float4 r;
  r.x = fmaxf(fmaxf(a.x, b.x), fmaxf(c.x, d.x));
  r.y = fmaxf(fmaxf(a.y, b.y), fmaxf(c.y, d.y));
  r.z = fmaxf(fmaxf(a.z, b.z), fmaxf(c.z, d.z));
  r.w = fmaxf(fmaxf(a.w, b.w), fmaxf(c.w, d.w));
  o[i] = r;
}

// ================= fallback path (previous passing version) =================
__global__ __launch_bounds__(256) void spn_scan_atomic(
    const float* __restrict__ x, const float* __restrict__ mask,
    unsigned* __restrict__ out) {
  const int bid = blockIdx.x;
  const int tid = threadIdx.x;
  __shared__ float tl[4][TCOLS][HW];
  __shared__ float hb[2][HW + 2];
  const size_t plane = (size_t)HW * HW;

  if (bid < 256) {
    const int dir = bid >> 7;
    const int rem = bid & 127;
    const int b = rem >> 5, ch = rem & 31;
    const bool rev = (dir == 1);
    const float* g1p = x + ((size_t)b * 12 * NF + (3 * dir + 0) * NF + ch) * plane;
    const float* g2p = x + ((size_t)b * 12 * NF + (3 * dir + 1) * NF + ch) * plane;
    const float* g3p = x + ((size_t)b * 12 * NF + (3 * dir + 2) * NF + ch) * plane;
    const float* mp  = mask + ((size_t)b * NF + ch) * plane;
    unsigned* op = out + ((size_t)b * NF + ch) * plane;

    for (int i = tid; i < 2 * (HW + 2); i += 256) (&hb[0][0])[i] = 0.0f;

    float hreg = 0.0f;
    int cur = 0;
    const int r0 = tid >> 1, cc = tid & 1;
    const float* ps[4] = {g1p, g2p, g3p, mp};
    for (int tile = 0; tile < HW / TCOLS; ++tile) {
      const int t0 = rev ? (HW - TCOLS - tile * TCOLS) : (tile * TCOLS);
      __syncthreads();
#pragma unroll
      for (int p = 0; p < 4; ++p) {
#pragma unroll
        for (int half = 0; half < 2; ++half) {
          const int r = r0 + half * 128;
          const float4 v = *(const float4*)(ps[p] + (size_t)r * HW + t0 + cc * 4);
          tl[p][cc * 4 + 0][r] = v.x;
          tl[p][cc * 4 + 1][r] = v.y;
          tl[p][cc * 4 + 2][r] = v.z;
          tl[p][cc * 4 + 3][r] = v.w;
        }
      }
      __syncthreads();
      for (int j = 0; j < TCOLS; ++j) {
        const int col = rev ? (TCOLS - 1 - j) : j;
        const int t = t0 + col;
        const float a  = tl[0][col][tid];
        const float g2 = tl[1][col][tid];
        const float c  = tl[2][col][tid];
        const float xm = tl[3][col][tid];
        const float hm = hb[cur][tid];
        const float hp = hb[cur][tid + 2];
        const float h = stepf(a, g2, c, xm, hm, hreg, hp);
        hb[cur ^ 1][tid + 1] = h;
        hreg = h;
        atomicMax(op + (size_t)tid * HW + t, enc(h));
        __syncthreads();
        cur ^= 1;
      }
    }
  } else {
    if (tid >= 64) return;
    const int lane = tid;
    const int vb = bid - 256;
    const int dir = 2 + (vb >> 7);
    const int rem = vb & 127;
    const int b = rem >> 5, ch = rem & 31;
    const bool rev = (dir == 3);
    const float* g1p = x + ((size_t)b * 12 * NF + (3 * dir + 0) * NF + ch) * plane;
    const float* g2p = x + ((size_t)b * 12 * NF + (3 * dir + 1) * NF + ch) * plane;
    const float* g3p = x + ((size_t)b * 12 * NF + (3 * dir + 2) * NF + ch) * plane;
    const float* mp  = mask + ((size_t)b * NF + ch) * plane;
    unsigned* op = out + ((size_t)b * NF + ch) * plane;

    float4 hv = {0.f, 0.f, 0.f, 0.f};
    int t = rev ? (HW - 1) : 0;
    const int koff = lane * 4;
    float4 a4 = *(const float4*)(g1p + (size_t)t * HW + koff);
    float4 b4 = *(const float4*)(g2p + (size_t)t * HW + koff);
    float4 c4 = *(const float4*)(g3p + (size_t)t * HW + koff);
    float4 x4 = *(const float4*)(mp  + (size_t)t * HW + koff);
    for (int step = 0; step < HW; ++step) {
      const float4 A = a4, B = b4, C = c4, X = x4;
      const int tn = rev ? (HW - 2 - step) : (step + 1);
      if (step + 1 < HW) {
        a4 = *(const float4*)(g1p + (size_t)tn * HW + koff);
        b4 = *(const float4*)(g2p + (size_t)tn * HW + koff);
        c4 = *(const float4*)(g3p + (size_t)tn * HW + koff);
        x4 = *(const float4*)(mp  + (size_t)tn * HW + koff);
      }
      float left = __shfl_up(hv.w, 1);
      if (lane == 0) left = 0.f;
      float right = __shfl_down(hv.x, 1);
      if (lane == 63) right = 0.f;
      float4 hn;
      hn.x = stepf(A.x, B.x, C.x, X.x, left, hv.x, hv.y);
      hn.y = stepf(A.y, B.y, C.y, X.y, hv.x, hv.y, hv.z);
      hn.z = stepf(A.z, B.z, C.z, X.z, hv.y, hv.z, hv.w);
      hn.w = stepf(A.w, B.w, C.w, X.w, hv.z, hv.w, right);
      unsigned* o = op + (size_t)t * HW + koff;
      atomicMax(o + 0, enc(hn.x));
      atomicMax(o + 1, enc(hn.y));
      atomicMax(o + 2, enc(hn.z));
      atomicMax(o + 3, enc(hn.w));
      hv = hn;
      t = tn;
    }
  }
}

__global__ __launch_bounds__(256) void spn_decode(unsigned* __restrict__ o) {
  const int i = blockIdx.x * 256 + threadIdx.x;
  uint4 v = ((uint4*)o)[i];
  float4 f;
  f.x = dec(v.x); f.y = dec(v.y); f.z = dec(v.z); f.w = dec(v.w);
  ((float4*)o)[i] = f;
}

extern "C" void kernel_launch(void* const* d_in, const int* in_sizes, int n_in,
                              void* d_out, int out_size, void* d_ws, size_t ws_size,
                              hipStream_t stream) {
  const float* x = (const float*)d_in[0];     // [4,384,256,256] f32
  const float* mask = (const float*)d_in[1];  // [4,32,256,256] f32
  (void)in_sizes; (void)n_in;
  const size_t need = (size_t)4 * out_size * sizeof(float);
  if (ws_size >= need) {
    float* ws = (float*)d_ws;
    spn_scan_ws<<<512, 64, 0, stream>>>(x, mask, ws);
    spn_combine<<<out_size / 1024, 256, 0, stream>>>(
        (const float4*)ws, (const float4*)(ws + (size_t)out_size),
        (const float4*)(ws + 2 * (size_t)out_size),
        (const float4*)(ws + 3 * (size_t)out_size), (float4*)d_out);
  } else {
    hipMemsetAsync(d_out, 0, (size_t)out_size * sizeof(float), stream);
    spn_scan_atomic<<<512, 256, 0, stream>>>(x, mask, (unsigned*)d_out);
    spn_decode<<<out_size / 1024, 256, 0, stream>>>((unsigned*)d_out);
  }
}

// Round 2
// 747.841 us; speedup vs baseline: 1.0130x; 1.0036x over previous
//
#include <hip/hip_runtime.h>
#include <stdint.h>

#define HW 256
#define NF 32
#define TCOLS 8
#define NT (HW / TCOLS)

// ---- monotone float<->uint encoding so atomicMax(uint) == float max ----
__device__ __forceinline__ unsigned enc(float f) {
  unsigned u = __float_as_uint(f);
  return u ^ (0x80000000u | (unsigned)((int)u >> 31));
}
__device__ __forceinline__ float dec(unsigned k) {
  unsigned b = (k & 0x80000000u) ? (k ^ 0x80000000u) : ~k;
  return __uint_as_float(b);
}

__device__ __forceinline__ float4 mk4(float a, float b, float c, float d) {
  float4 v; v.x = a; v.y = b; v.z = c; v.w = d; return v;
}

// one recurrence element: normalize gates, then
// h = (1-a-b-c)*x + a*h[k-1] + b*h[k] + c*h[k+1]
__device__ __forceinline__ float stepf(float a, float b, float c, float xm,
                                       float hm, float hc, float hp) {
  float s = fabsf(a) + fabsf(b) + fabsf(c) + 1e-7f;
  float inv = __builtin_amdgcn_rcpf(s);
  if (s < 1.0f) inv = 1.0f;
  a *= inv; b *= inv; c *= inv;
  float h = (1.0f - a - b - c) * xm;
  h = fmaf(a, hm, h);
  h = fmaf(b, hc, h);
  h = fmaf(c, hp, h);
  return h;
}

// element select by literal component index
#define EL_0(v) (v).x
#define EL_1(v) (v).y
#define EL_2(v) (v).z
#define EL_3(v) (v).w
#define EL(v, cc) EL_##cc(v)

// stage one 8-col tile (4 arrays x 256 rows x 8 cols = 32 KB) into LDS
// buffer `par` via global_load_lds DMA. LDS write is linear (chunk = lane);
// the chunk swizzle (chunk' = chunk ^ ((chunk>>3)&7)) is realized by
// permuting the per-lane GLOBAL source address (same memory segments, lanes
// reordered within groups of 8 -> identical coalescing).
__device__ __forceinline__ void stage_tile(const float* const* ps,
                                           float (*B)[4][2048], int par,
                                           int t0, int srow, int scol) {
#pragma unroll
  for (int p = 0; p < 4; ++p) {
#pragma unroll
    for (int P = 0; P < 8; ++P) {
      const float* g = ps[p] + (size_t)(P * 32 + srow) * HW + t0 + scol;
      __builtin_amdgcn_global_load_lds(
          (const __attribute__((address_space(1))) uint32_t*)g,
          (__attribute__((address_space(3))) uint32_t*)&B[par][p][P * 256],
          16, 0, 0);
    }
  }
}

// ======================= fast path: per-direction ws buffers ================
// 512 single-wave blocks:
//   blocks 0..255   = horizontal planes (dir 0 fwd / 1 rev): DMA-staged LDS
//                     tiles, lane owns rows 4l..4l+3, halo via shfl.
//   blocks 256..511 = vertical planes (dir 2 fwd / 3 rev): coalesced direct
//                     loads, lane owns cols 4l..4l+3, halo via shfl.
// bid<256 vs >=256 split keeps H+V paired per CU under round-robin dispatch
// (CU c on XCD x tends to get bids x+8c and x+8c+256).

#define COLF(jg, cc)                                                        \
  {                                                                         \
    float left = __shfl_up(hv.w, 1);                                        \
    if (lane == 0) left = 0.f;                                              \
    float right = __shfl_down(hv.x, 1);                                     \
    if (lane == 63) right = 0.f;                                            \
    float4 hn;                                                              \
    hn.x = stepf(EL(fa0, cc), EL(fb0, cc), EL(fc0, cc), EL(fx0, cc), left, hv.x, hv.y);  \
    hn.y = stepf(EL(fa1, cc), EL(fb1, cc), EL(fc1, cc), EL(fx1, cc), hv.x, hv.y, hv.z);  \
    hn.z = stepf(EL(fa2, cc), EL(fb2, cc), EL(fc2, cc), EL(fx2, cc), hv.y, hv.z, hv.w);  \
    hn.w = stepf(EL(fa3, cc), EL(fb3, cc), EL(fc3, cc), EL(fx3, cc), hv.z, hv.w, right); \
    res[(jg) * 4 + (cc)] = hn;                                              \
    hv = hn;                                                                \
  }

#define LOADG(par, jg)                                                      \
  {                                                                         \
    const char* b0 = (const char*)&B[par][0][0];                            \
    const char* b1 = (const char*)&B[par][1][0];                            \
    const char* b2 = (const char*)&B[par][2][0];                            \
    const char* b3 = (const char*)&B[par][3][0];                            \
    fa0 = *(const float4*)(b0 + rb[0][jg]);                                 \
    fa1 = *(const float4*)(b0 + rb[1][jg]);                                 \
    fa2 = *(const float4*)(b0 + rb[2][jg]);                                 \
    fa3 = *(const float4*)(b0 + rb[3][jg]);                                 \
    fb0 = *(const float4*)(b1 + rb[0][jg]);                                 \
    fb1 = *(const float4*)(b1 + rb[1][jg]);                                 \
    fb2 = *(const float4*)(b1 + rb[2][jg]);                                 \
    fb3 = *(const float4*)(b1 + rb[3][jg]);                                 \
    fc0 = *(const float4*)(b2 + rb[0][jg]);                                 \
    fc1 = *(const float4*)(b2 + rb[1][jg]);                                 \
    fc2 = *(const float4*)(b2 + rb[2][jg]);                                 \
    fc3 = *(const float4*)(b2 + rb[3][jg]);                                 \
    fx0 = *(const float4*)(b3 + rb[0][jg]);                                 \
    fx1 = *(const float4*)(b3 + rb[1][jg]);                                 \
    fx2 = *(const float4*)(b3 + rb[2][jg]);                                 \
    fx3 = *(const float4*)(b3 + rb[3][jg]);                                 \
  }

__global__ __launch_bounds__(64, 1) void spn_scan_ws(
    const float* __restrict__ x, const float* __restrict__ mask,
    float* __restrict__ ws) {
  const int bid = blockIdx.x;
  const int lane = threadIdx.x;  // 0..63, one wave per block
  const size_t plane = (size_t)HW * HW;
  const size_t PBUF = (size_t)4 * NF * plane;  // one direction buffer
  __shared__ __align__(16) float B[2][4][2048];  // double-buffered tile, 64 KB

  if (bid < 256) {
    // ---------------- horizontal: scan w, cross dim = rows (h) -------------
    const int dir = bid >> 7;
    const int rem = bid & 127;
    const int b = rem >> 5, ch = rem & 31;
    const bool rev = (dir == 1);
    const float* g1p = x + ((size_t)b * 12 * NF + (3 * dir + 0) * NF + ch) * plane;
    const float* g2p = x + ((size_t)b * 12 * NF + (3 * dir + 1) * NF + ch) * plane;
    const float* g3p = x + ((size_t)b * 12 * NF + (3 * dir + 2) * NF + ch) * plane;
    const float* mp  = mask + ((size_t)b * NF + ch) * plane;
    float* wdir = ws + (size_t)dir * PBUF + ((size_t)b * NF + ch) * plane;
    const float* ps[4] = {g1p, g2p, g3p, mp};

    // staging lane permutation (pre-swizzled global source; involution)
    const int lp = lane ^ ((lane >> 3) & 7);
    const int srow = lp >> 1;        // 0..31 within 32-row stripe
    const int scol = (lp & 1) * 4;   // 0 or 4

    // per-lane LDS read byte offsets (within one array-plane):
    // chunk' = (8*lane + 2*i + jg) ^ (lane&7); byte = chunk'*16.
    // Bank spread: chunk'%8 = (2i+jg)^(lane&7) -> 8-way (16B-granule floor).
    int rb[4][2];
#pragma unroll
    for (int i = 0; i < 4; ++i)
#pragma unroll
      for (int jg = 0; jg < 2; ++jg)
        rb[i][jg] = ((8 * lane + 2 * i + jg) ^ (lane & 7)) * 16;

    float4 hv = mk4(0.f, 0.f, 0.f, 0.f);
    float4 res[TCOLS];
    float4 fa0, fa1, fa2, fa3, fb0, fb1, fb2, fb3;
    float4 fc0, fc1, fc2, fc3, fx0, fx1, fx2, fx3;

    stage_tile(ps, B, 0, rev ? (HW - TCOLS) : 0, srow, scol);

    for (int k = 0; k < NT; ++k) {
      const int par = k & 1;
      // counted wait: this tile's 32 DMAs are the oldest; up to 8 young
      // output stores may still be in flight (never drain to 0 mid-loop).
      if (k == 0) {
        asm volatile("s_waitcnt vmcnt(0)" ::: "memory");
      } else {
        asm volatile("s_waitcnt vmcnt(8)" ::: "memory");
      }
      __builtin_amdgcn_sched_barrier(0);
      if (k + 1 < NT) {  // issue next tile's DMAs; they age one full compute
        const int t0n = rev ? (HW - TCOLS - (k + 1) * TCOLS) : ((k + 1) * TCOLS);
        stage_tile(ps, B, par ^ 1, t0n, srow, scol);
      }
      // keep DMA issue ahead of the stores in program order (vmcnt counting)
      __builtin_amdgcn_sched_barrier(0);

      if (!rev) {
        LOADG(par, 0); COLF(0, 0) COLF(0, 1) COLF(0, 2) COLF(0, 3)
        LOADG(par, 1); COLF(1, 0) COLF(1, 1) COLF(1, 2) COLF(1, 3)
      } else {
        LOADG(par, 1); COLF(1, 3) COLF(1, 2) COLF(1, 1) COLF(1, 0)
        LOADG(par, 0); COLF(0, 3) COLF(0, 2) COLF(0, 1) COLF(0, 0)
      }

      const int t0c = rev ? (HW - TCOLS - k * TCOLS) : (k * TCOLS);
      float* wr = wdir + (size_t)(4 * lane) * HW + t0c;
      *(float4*)(wr)              = mk4(res[0].x, res[1].x, res[2].x, res[3].x);
      *(float4*)(wr + 4)          = mk4(res[4].x, res[5].x, res[6].x, res[7].x);
      *(float4*)(wr + HW)         = mk4(res[0].y, res[1].y, res[2].y, res[3].y);
      *(float4*)(wr + HW + 4)     = mk4(res[4].y, res[5].y, res[6].y, res[7].y);
      *(float4*)(wr + 2 * HW)     = mk4(res[0].z, res[1].z, res[2].z, res[3].z);
      *(float4*)(wr + 2 * HW + 4) = mk4(res[4].z, res[5].z, res[6].z, res[7].z);
      *(float4*)(wr + 3 * HW)     = mk4(res[0].w, res[1].w, res[2].w, res[3].w);
      *(float4*)(wr + 3 * HW + 4) = mk4(res[4].w, res[5].w, res[6].w, res[7].w);
    }
  } else {
    // ---------------- vertical: scan h, cross dim = cols (w) ---------------
    const int sid = bid - 256;  // 0..255
    const int dir = 2 + (sid >> 7);
    const int rem = sid & 127;
    const int b = rem >> 5, ch = rem & 31;
    const bool rev = (dir == 3);
    const float* g1p = x + ((size_t)b * 12 * NF + (3 * dir + 0) * NF + ch) * plane;
    const float* g2p = x + ((size_t)b * 12 * NF + (3 * dir + 1) * NF + ch) * plane;
    const float* g3p = x + ((size_t)b * 12 * NF + (3 * dir + 2) * NF + ch) * plane;
    const float* mp  = mask + ((size_t)b * NF + ch) * plane;
    float* wdir = ws + (size_t)dir * PBUF + ((size_t)b * NF + ch) * plane;

    const int koff = lane * 4;  // lane owns w = 4*lane .. 4*lane+3
    float4 hv = mk4(0.f, 0.f, 0.f, 0.f);
    float4 Ab[4], Bb[4], Cb[4], Xb[4];  // depth-4 prefetch ring
#pragma unroll
    for (int p = 0; p < 4; ++p) {
      const int t = rev ? (HW - 1 - p) : p;
      const size_t ro = (size_t)t * HW + koff;
      Ab[p] = *(const float4*)(g1p + ro);
      Bb[p] = *(const float4*)(g2p + ro);
      Cb[p] = *(const float4*)(g3p + ro);
      Xb[p] = *(const float4*)(mp + ro);
    }

#define VSTEP(s, ph)                                                        \
  {                                                                         \
    const int t = rev ? (HW - 1 - (s)) : (s);                               \
    const float4 A = Ab[ph], Bv = Bb[ph], Cv = Cb[ph], X = Xb[ph];          \
    float left = __shfl_up(hv.w, 1);                                        \
    if (lane == 0) left = 0.f;                                              \
    float right = __shfl_down(hv.x, 1);                                     \
    if (lane == 63) right = 0.f;                                            \
    float4 hn;                                                              \
    hn.x = stepf(A.x, Bv.x, Cv.x, X.x, left, hv.x, hv.y);                   \
    hn.y = stepf(A.y, Bv.y, Cv.y, X.y, hv.x, hv.y, hv.z);                   \
    hn.z = stepf(A.z, Bv.z, Cv.z, X.z, hv.y, hv.z, hv.w);                   \
    hn.w = stepf(A.w, Bv.w, Cv.w, X.w, hv.z, hv.w, right);                  \
    *(float4*)(wdir + (size_t)t * HW + koff) = hn;                          \
    const int sn = (s) + 4;                                                 \
    if (sn < HW) {                                                          \
      const int tn = rev ? (HW - 1 - sn) : sn;                              \
      const size_t ro = (size_t)tn * HW + koff;                             \
      Ab[ph] = *(const float4*)(g1p + ro);                                  \
      Bb[ph] = *(const float4*)(g2p + ro);                                  \
      Cb[ph] = *(const float4*)(g3p + ro);                                  \
      Xb[ph] = *(const float4*)(mp + ro);                                   \
    }                                                                       \
    hv = hn;                                                                \
  }

    for (int s = 0; s < HW; s += 4) {
      VSTEP(s + 0, 0);
      VSTEP(s + 1, 1);
      VSTEP(s + 2, 2);
      VSTEP(s + 3, 3);
    }
#undef VSTEP
  }
}

__global__ __launch_bounds__(256) void spn_combine(
    const float4* __restrict__ w0, const float4* __restrict__ w1,
    const float4* __restrict__ w2, const float4* __restrict__ w3,
    float4* __restrict__ o) {
  const int i = blockIdx.x * 256 + threadIdx.x;
  const float4 a = w0[i], b = w1[i], c = w2[i], d = w3[i];
  float4 r;
  r.x = fmaxf(fmaxf(a.x, b.x), fmaxf(c.x, d.x));
  r.y = fmaxf(fmaxf(a.y, b.y), fmaxf(c.y, d.y));
  r.z = fmaxf(fmaxf(a.z, b.z), fmaxf(c.z, d.z));
  r.w = fmaxf(fmaxf(a.w, b.w), fmaxf(c.w, d.w));
  o[i] = r;
}

// ================= fallback path (previous passing version) =================
__global__ __launch_bounds__(256) void spn_scan_atomic(
    const float* __restrict__ x, const float* __restrict__ mask,
    unsigned* __restrict__ out) {
  const int bid = blockIdx.x;
  const int tid = threadIdx.x;
  __shared__ float tl[4][TCOLS][HW];
  __shared__ float hb[2][HW + 2];
  const size_t plane = (size_t)HW * HW;

  if (bid < 256) {
    const int dir = bid >> 7;
    const int rem = bid & 127;
    const int b = rem >> 5, ch = rem & 31;
    const bool rev = (dir == 1);
    const float* g1p = x + ((size_t)b * 12 * NF + (3 * dir + 0) * NF + ch) * plane;
    const float* g2p = x + ((size_t)b * 12 * NF + (3 * dir + 1) * NF + ch) * plane;
    const float* g3p = x + ((size_t)b * 12 * NF + (3 * dir + 2) * NF + ch) * plane;
    const float* mp  = mask + ((size_t)b * NF + ch) * plane;
    unsigned* op = out + ((size_t)b * NF + ch) * plane;

    for (int i = tid; i < 2 * (HW + 2); i += 256) (&hb[0][0])[i] = 0.0f;

    float hreg = 0.0f;
    int cur = 0;
    const int r0 = tid >> 1, cc = tid & 1;
    const float* ps[4] = {g1p, g2p, g3p, mp};
    for (int tile = 0; tile < HW / TCOLS; ++tile) {
      const int t0 = rev ? (HW - TCOLS - tile * TCOLS) : (tile * TCOLS);
      __syncthreads();
#pragma unroll
      for (int p = 0; p < 4; ++p) {
#pragma unroll
        for (int half = 0; half < 2; ++half) {
          const int r = r0 + half * 128;
          const float4 v = *(const float4*)(ps[p] + (size_t)r * HW + t0 + cc * 4);
          tl[p][cc * 4 + 0][r] = v.x;
          tl[p][cc * 4 + 1][r] = v.y;
          tl[p][cc * 4 + 2][r] = v.z;
          tl[p][cc * 4 + 3][r] = v.w;
        }
      }
      __syncthreads();
      for (int j = 0; j < TCOLS; ++j) {
        const int col = rev ? (TCOLS - 1 - j) : j;
        const int t = t0 + col;
        const float a  = tl[0][col][tid];
        const float g2 = tl[1][col][tid];
        const float c  = tl[2][col][tid];
        const float xm = tl[3][col][tid];
        const float hm = hb[cur][tid];
        const float hp = hb[cur][tid + 2];
        const float h = stepf(a, g2, c, xm, hm, hreg, hp);
        hb[cur ^ 1][tid + 1] = h;
        hreg = h;
        atomicMax(op + (size_t)tid * HW + t, enc(h));
        __syncthreads();
        cur ^= 1;
      }
    }
  } else {
    if (tid >= 64) return;
    const int lane = tid;
    const int vb = bid - 256;
    const int dir = 2 + (vb >> 7);
    const int rem = vb & 127;
    const int b = rem >> 5, ch = rem & 31;
    const bool rev = (dir == 3);
    const float* g1p = x + ((size_t)b * 12 * NF + (3 * dir + 0) * NF + ch) * plane;
    const float* g2p = x + ((size_t)b * 12 * NF + (3 * dir + 1) * NF + ch) * plane;
    const float* g3p = x + ((size_t)b * 12 * NF + (3 * dir + 2) * NF + ch) * plane;
    const float* mp  = mask + ((size_t)b * NF + ch) * plane;
    unsigned* op = out + ((size_t)b * NF + ch) * plane;

    float4 hv = {0.f, 0.f, 0.f, 0.f};
    int t = rev ? (HW - 1) : 0;
    const int koff = lane * 4;
    float4 a4 = *(const float4*)(g1p + (size_t)t * HW + koff);
    float4 b4 = *(const float4*)(g2p + (size_t)t * HW + koff);
    float4 c4 = *(const float4*)(g3p + (size_t)t * HW + koff);
    float4 x4 = *(const float4*)(mp  + (size_t)t * HW + koff);
    for (int step = 0; step < HW; ++step) {
      const float4 A = a4, B = b4, C = c4, X = x4;
      const int tn = rev ? (HW - 2 - step) : (step + 1);
      if (step + 1 < HW) {
        a4 = *(const float4*)(g1p + (size_t)tn * HW + koff);
        b4 = *(const float4*)(g2p + (size_t)tn * HW + koff);
        c4 = *(const float4*)(g3p + (size_t)tn * HW + koff);
        x4 = *(const float4*)(mp  + (size_t)tn * HW + koff);
      }
      float left = __shfl_up(hv.w, 1);
      if (lane == 0) left = 0.f;
      float right = __shfl_down(hv.x, 1);
      if (lane == 63) right = 0.f;
      float4 hn;
      hn.x = stepf(A.x, B.x, C.x, X.x, left, hv.x, hv.y);
      hn.y = stepf(A.y, B.y, C.y, X.y, hv.x, hv.y, hv.z);
      hn.z = stepf(A.z, B.z, C.z, X.z, hv.y, hv.z, hv.w);
      hn.w = stepf(A.w, B.w, C.w, X.w, hv.z, hv.w, right);
      unsigned* o = op + (size_t)t * HW + koff;
      atomicMax(o + 0, enc(hn.x));
      atomicMax(o + 1, enc(hn.y));
      atomicMax(o + 2, enc(hn.z));
      atomicMax(o + 3, enc(hn.w));
      hv = hn;
      t = tn;
    }
  }
}

__global__ __launch_bounds__(256) void spn_decode(unsigned* __restrict__ o) {
  const int i = blockIdx.x * 256 + threadIdx.x;
  uint4 v = ((uint4*)o)[i];
  float4 f;
  f.x = dec(v.x); f.y = dec(v.y); f.z = dec(v.z); f.w = dec(v.w);
  ((float4*)o)[i] = f;
}

extern "C" void kernel_launch(void* const* d_in, const int* in_sizes, int n_in,
                              void* d_out, int out_size, void* d_ws, size_t ws_size,
                              hipStream_t stream) {
  const float* x = (const float*)d_in[0];     // [4,384,256,256] f32
  const float* mask = (const float*)d_in[1];  // [4,32,256,256] f32
  (void)in_sizes; (void)n_in;
  const size_t need = (size_t)4 * out_size * sizeof(float);
  if (ws_size >= need) {
    float* ws = (float*)d_ws;
    spn_scan_ws<<<512, 64, 0, stream>>>(x, mask, ws);
    spn_combine<<<out_size / 1024, 256, 0, stream>>>(
        (const float4*)ws, (const float4*)(ws + (size_t)out_size),
        (const float4*)(ws + 2 * (size_t)out_size),
        (const float4*)(ws + 3 * (size_t)out_size), (float4*)d_out);
  } else {
    hipMemsetAsync(d_out, 0, (size_t)out_size * sizeof(float), stream);
    spn_scan_atomic<<<512, 256, 0, stream>>>(x, mask, (unsigned*)d_out);
    spn_decode<<<out_size / 1024, 256, 0, stream>>>((unsigned*)d_out);
  }
}

// Round 3
// 680.815 us; speedup vs baseline: 1.1127x; 1.0984x over previous
//
#include <hip/hip_runtime.h>
#include <stdint.h>

#define HW 256
#define NF 32
#define TCOLS 8
#define NT (HW / TCOLS)

// ---- monotone float<->uint encoding so atomicMax(uint) == float max ----
__device__ __forceinline__ unsigned enc(float f) {
  unsigned u = __float_as_uint(f);
  return u ^ (0x80000000u | (unsigned)((int)u >> 31));
}
__device__ __forceinline__ float dec(unsigned k) {
  unsigned b = (k & 0x80000000u) ? (k ^ 0x80000000u) : ~k;
  return __uint_as_float(b);
}

__device__ __forceinline__ float4 mk4(float a, float b, float c, float d) {
  float4 v; v.x = a; v.y = b; v.z = c; v.w = d; return v;
}

// one recurrence element: normalize gates, then
// h = (1-a-b-c)*x + a*h[k-1] + b*h[k] + c*h[k+1]
__device__ __forceinline__ float stepf(float a, float b, float c, float xm,
                                       float hm, float hc, float hp) {
  float s = fabsf(a) + fabsf(b) + fabsf(c) + 1e-7f;
  float inv = __builtin_amdgcn_rcpf(s);
  if (s < 1.0f) inv = 1.0f;
  a *= inv; b *= inv; c *= inv;
  float h = (1.0f - a - b - c) * xm;
  h = fmaf(a, hm, h);
  h = fmaf(b, hc, h);
  h = fmaf(c, hp, h);
  return h;
}

// element select by literal component index
#define EL_0(v) (v).x
#define EL_1(v) (v).y
#define EL_2(v) (v).z
#define EL_3(v) (v).w
#define EL(v, cc) EL_##cc(v)

// stage one 8-col tile (4 arrays x 256 rows x 8 cols = 32 KB) into LDS
// buffer `par` via global_load_lds DMA. LDS write is linear (chunk = lane);
// the chunk swizzle (chunk' = chunk ^ ((chunk>>3)&7)) is realized by
// permuting the per-lane GLOBAL source address (involution; same segments).
__device__ __forceinline__ void stage_tile(const float* const* ps,
                                           float (*B)[4][2048], int par,
                                           int t0, int srow, int scol) {
#pragma unroll
  for (int p = 0; p < 4; ++p) {
#pragma unroll
    for (int P = 0; P < 8; ++P) {
      const float* g = ps[p] + (size_t)(P * 32 + srow) * HW + t0 + scol;
      __builtin_amdgcn_global_load_lds(
          (const __attribute__((address_space(1))) uint32_t*)g,
          (__attribute__((address_space(3))) uint32_t*)&B[par][p][P * 256],
          16, 0, 0);
    }
  }
}

// ======================= fast path: per-direction ws buffers ================
// 512 single-wave blocks:
//   blocks 0..255   = horizontal planes (dir 0 fwd / 1 rev): DMA-staged LDS
//                     tiles, lane owns rows 4l..4l+3, halo via shfl.
//   blocks 256..511 = vertical planes (dir 2 fwd / 3 rev): coalesced direct
//                     loads, depth-8 ring, lane owns cols 4l..4l+3.
// ALL steady-state loops are straight-line with UNCONDITIONAL prefetch
// (prologue/epilogue peeled) so the waitcnt pass can count vm-ops exactly —
// conditional prefetch forces conservative vmcnt(0) drains (the round-0..2
// plateau).

#define COLF(jg, cc)                                                        \
  {                                                                         \
    float left = __shfl_up(hv.w, 1);                                        \
    if (lane == 0) left = 0.f;                                              \
    float right = __shfl_down(hv.x, 1);                                     \
    if (lane == 63) right = 0.f;                                            \
    float4 hn;                                                              \
    hn.x = stepf(EL(fa0, cc), EL(fb0, cc), EL(fc0, cc), EL(fx0, cc), left, hv.x, hv.y);  \
    hn.y = stepf(EL(fa1, cc), EL(fb1, cc), EL(fc1, cc), EL(fx1, cc), hv.x, hv.y, hv.z);  \
    hn.z = stepf(EL(fa2, cc), EL(fb2, cc), EL(fc2, cc), EL(fx2, cc), hv.y, hv.z, hv.w);  \
    hn.w = stepf(EL(fa3, cc), EL(fb3, cc), EL(fc3, cc), EL(fx3, cc), hv.z, hv.w, right); \
    res[(jg) * 4 + (cc)] = hn;                                              \
    hv = hn;                                                                \
  }

#define LOADG(par, jg)                                                      \
  {                                                                         \
    const char* b0 = (const char*)&B[par][0][0];                            \
    const char* b1 = (const char*)&B[par][1][0];                            \
    const char* b2 = (const char*)&B[par][2][0];                            \
    const char* b3 = (const char*)&B[par][3][0];                            \
    fa0 = *(const float4*)(b0 + rb[0][jg]);                                 \
    fa1 = *(const float4*)(b0 + rb[1][jg]);                                 \
    fa2 = *(const float4*)(b0 + rb[2][jg]);                                 \
    fa3 = *(const float4*)(b0 + rb[3][jg]);                                 \
    fb0 = *(const float4*)(b1 + rb[0][jg]);                                 \
    fb1 = *(const float4*)(b1 + rb[1][jg]);                                 \
    fb2 = *(const float4*)(b1 + rb[2][jg]);                                 \
    fb3 = *(const float4*)(b1 + rb[3][jg]);                                 \
    fc0 = *(const float4*)(b2 + rb[0][jg]);                                 \
    fc1 = *(const float4*)(b2 + rb[1][jg]);                                 \
    fc2 = *(const float4*)(b2 + rb[2][jg]);                                 \
    fc3 = *(const float4*)(b2 + rb[3][jg]);                                 \
    fx0 = *(const float4*)(b3 + rb[0][jg]);                                 \
    fx1 = *(const float4*)(b3 + rb[1][jg]);                                 \
    fx2 = *(const float4*)(b3 + rb[2][jg]);                                 \
    fx3 = *(const float4*)(b3 + rb[3][jg]);                                 \
  }

// H-path per-tile compute + store (tile index kk, buffer par)
#define HTILE(kk, par)                                                      \
  {                                                                         \
    if (!rev) {                                                             \
      LOADG(par, 0); COLF(0, 0) COLF(0, 1) COLF(0, 2) COLF(0, 3)            \
      LOADG(par, 1); COLF(1, 0) COLF(1, 1) COLF(1, 2) COLF(1, 3)            \
    } else {                                                                \
      LOADG(par, 1); COLF(1, 3) COLF(1, 2) COLF(1, 1) COLF(1, 0)            \
      LOADG(par, 0); COLF(0, 3) COLF(0, 2) COLF(0, 1) COLF(0, 0)            \
    }                                                                       \
    const int t0c = rev ? (HW - TCOLS - (kk) * TCOLS) : ((kk) * TCOLS);     \
    float* wr = wdir + (size_t)(4 * lane) * HW + t0c;                       \
    *(float4*)(wr)              = mk4(res[0].x, res[1].x, res[2].x, res[3].x); \
    *(float4*)(wr + 4)          = mk4(res[4].x, res[5].x, res[6].x, res[7].x); \
    *(float4*)(wr + HW)         = mk4(res[0].y, res[1].y, res[2].y, res[3].y); \
    *(float4*)(wr + HW + 4)     = mk4(res[4].y, res[5].y, res[6].y, res[7].y); \
    *(float4*)(wr + 2 * HW)     = mk4(res[0].z, res[1].z, res[2].z, res[3].z); \
    *(float4*)(wr + 2 * HW + 4) = mk4(res[4].z, res[5].z, res[6].z, res[7].z); \
    *(float4*)(wr + 3 * HW)     = mk4(res[0].w, res[1].w, res[2].w, res[3].w); \
    *(float4*)(wr + 3 * HW + 4) = mk4(res[4].w, res[5].w, res[6].w, res[7].w); \
  }

__global__ __launch_bounds__(64, 1) void spn_scan_ws(
    const float* __restrict__ x, const float* __restrict__ mask,
    float* __restrict__ ws) {
  const int bid = blockIdx.x;
  const int lane = threadIdx.x;  // 0..63, one wave per block
  const size_t plane = (size_t)HW * HW;
  const size_t PBUF = (size_t)4 * NF * plane;  // one direction buffer
  __shared__ __align__(16) float B[2][4][2048];  // double-buffered tile, 64 KB

  if (bid < 256) {
    // ---------------- horizontal: scan w, cross dim = rows (h) -------------
    const int dir = bid >> 7;
    const int rem = bid & 127;
    const int b = rem >> 5, ch = rem & 31;
    const bool rev = (dir == 1);
    const float* g1p = x + ((size_t)b * 12 * NF + (3 * dir + 0) * NF + ch) * plane;
    const float* g2p = x + ((size_t)b * 12 * NF + (3 * dir + 1) * NF + ch) * plane;
    const float* g3p = x + ((size_t)b * 12 * NF + (3 * dir + 2) * NF + ch) * plane;
    const float* mp  = mask + ((size_t)b * NF + ch) * plane;
    float* wdir = ws + (size_t)dir * PBUF + ((size_t)b * NF + ch) * plane;
    const float* ps[4] = {g1p, g2p, g3p, mp};

    // staging lane permutation (pre-swizzled global source; involution)
    const int lp = lane ^ ((lane >> 3) & 7);
    const int srow = lp >> 1;        // 0..31 within 32-row stripe
    const int scol = (lp & 1) * 4;   // 0 or 4

    // per-lane LDS read byte offsets (within one array-plane):
    // chunk' = (8*lane + 2*i + jg) ^ (lane&7); byte = chunk'*16.
    int rb[4][2];
#pragma unroll
    for (int i = 0; i < 4; ++i)
#pragma unroll
      for (int jg = 0; jg < 2; ++jg)
        rb[i][jg] = ((8 * lane + 2 * i + jg) ^ (lane & 7)) * 16;

    float4 hv = mk4(0.f, 0.f, 0.f, 0.f);
    float4 res[TCOLS];
    float4 fa0, fa1, fa2, fa3, fb0, fb1, fb2, fb3;
    float4 fc0, fc1, fc2, fc3, fx0, fx1, fx2, fx3;

    const int stp = rev ? -TCOLS : TCOLS;
    const int t00 = rev ? (HW - TCOLS) : 0;

    // ---- prologue (peeled k=0): stage tiles 0 and 1, wait tile 0 only ----
    stage_tile(ps, B, 0, t00, srow, scol);
    stage_tile(ps, B, 1, t00 + stp, srow, scol);
    asm volatile("s_waitcnt vmcnt(32)" ::: "memory");  // tile0 done, tile1 flies
    __builtin_amdgcn_sched_barrier(0);
    HTILE(0, 0);

    // ---- steady state k = 1 .. NT-2: straight-line, unconditional stage ---
    for (int k = 1; k <= NT - 2; ++k) {
      const int par = k & 1;
      // in-flight: DMA_k (32, oldest) + stores_{k-1} (8) -> wait leaves 8
      asm volatile("s_waitcnt vmcnt(8)" ::: "memory");
      __builtin_amdgcn_sched_barrier(0);
      stage_tile(ps, B, par ^ 1, t00 + (k + 1) * stp, srow, scol);
      __builtin_amdgcn_sched_barrier(0);
      HTILE(k, par);
    }

    // ---- epilogue (peeled k=NT-1): no stage ----
    asm volatile("s_waitcnt vmcnt(8)" ::: "memory");
    __builtin_amdgcn_sched_barrier(0);
    HTILE(NT - 1, (NT - 1) & 1);
  } else {
    // ---------------- vertical: scan h, cross dim = cols (w) ---------------
    const int sid = bid - 256;  // 0..255
    const int dir = 2 + (sid >> 7);
    const int rem = sid & 127;
    const int b = rem >> 5, ch = rem & 31;
    const bool rev = (dir == 3);
    const float* g1p = x + ((size_t)b * 12 * NF + (3 * dir + 0) * NF + ch) * plane;
    const float* g2p = x + ((size_t)b * 12 * NF + (3 * dir + 1) * NF + ch) * plane;
    const float* g3p = x + ((size_t)b * 12 * NF + (3 * dir + 2) * NF + ch) * plane;
    const float* mp  = mask + ((size_t)b * NF + ch) * plane;
    float* wdir = ws + (size_t)dir * PBUF + ((size_t)b * NF + ch) * plane;

    const int koff = lane * 4;  // lane owns w = 4*lane .. 4*lane+3
    float4 hv = mk4(0.f, 0.f, 0.f, 0.f);
    float4 Ab[8], Bb[8], Cb[8], Xb[8];  // depth-8 prefetch ring
#pragma unroll
    for (int p = 0; p < 8; ++p) {
      const int t = rev ? (HW - 1 - p) : p;
      const size_t ro = (size_t)t * HW + koff;
      Ab[p] = *(const float4*)(g1p + ro);
      Bb[p] = *(const float4*)(g2p + ro);
      Cb[p] = *(const float4*)(g3p + ro);
      Xb[p] = *(const float4*)(mp + ro);
    }

// compute step s from ring phase ph, then UNCONDITIONALLY reload phase ph
// with step s+8 (caller guarantees s+8 < HW)
#define VSTEP_L(s, ph)                                                      \
  {                                                                         \
    const int t = rev ? (HW - 1 - (s)) : (s);                               \
    const float4 A = Ab[ph], Bv = Bb[ph], Cv = Cb[ph], X = Xb[ph];          \
    float left = __shfl_up(hv.w, 1);                                        \
    if (lane == 0) left = 0.f;                                              \
    float right = __shfl_down(hv.x, 1);                                     \
    if (lane == 63) right = 0.f;                                            \
    float4 hn;                                                              \
    hn.x = stepf(A.x, Bv.x, Cv.x, X.x, left, hv.x, hv.y);                   \
    hn.y = stepf(A.y, Bv.y, Cv.y, X.y, hv.x, hv.y, hv.z);                   \
    hn.z = stepf(A.z, Bv.z, Cv.z, X.z, hv.y, hv.z, hv.w);                   \
    hn.w = stepf(A.w, Bv.w, Cv.w, X.w, hv.z, hv.w, right);                  \
    *(float4*)(wdir + (size_t)t * HW + koff) = hn;                          \
    const int tn = rev ? (HW - 1 - ((s) + 8)) : ((s) + 8);                  \
    const size_t ro = (size_t)tn * HW + koff;                               \
    Ab[ph] = *(const float4*)(g1p + ro);                                    \
    Bb[ph] = *(const float4*)(g2p + ro);                                    \
    Cb[ph] = *(const float4*)(g3p + ro);                                    \
    Xb[ph] = *(const float4*)(mp + ro);                                     \
    hv = hn;                                                                \
  }

// compute only (peeled epilogue)
#define VSTEP_N(s, ph)                                                      \
  {                                                                         \
    const int t = rev ? (HW - 1 - (s)) : (s);                               \
    const float4 A = Ab[ph], Bv = Bb[ph], Cv = Cb[ph], X = Xb[ph];          \
    float left = __shfl_up(hv.w, 1);                                        \
    if (lane == 0) left = 0.f;                                              \
    float right = __shfl_down(hv.x, 1);                                     \
    if (lane == 63) right = 0.f;                                            \
    float4 hn;                                                              \
    hn.x = stepf(A.x, Bv.x, Cv.x, X.x, left, hv.x, hv.y);                   \
    hn.y = stepf(A.y, Bv.y, Cv.y, X.y, hv.x, hv.y, hv.z);                   \
    hn.z = stepf(A.z, Bv.z, Cv.z, X.z, hv.y, hv.z, hv.w);                   \
    hn.w = stepf(A.w, Bv.w, Cv.w, X.w, hv.z, hv.w, right);                  \
    *(float4*)(wdir + (size_t)t * HW + koff) = hn;                          \
    hv = hn;                                                                \
  }

    // main loop: steps 0..247, reloads 8..255 — all unconditional
    for (int s = 0; s <= HW - 16; s += 8) {
      VSTEP_L(s + 0, 0);
      VSTEP_L(s + 1, 1);
      VSTEP_L(s + 2, 2);
      VSTEP_L(s + 3, 3);
      VSTEP_L(s + 4, 4);
      VSTEP_L(s + 5, 5);
      VSTEP_L(s + 6, 6);
      VSTEP_L(s + 7, 7);
    }
    // epilogue: steps 248..255, no reloads
    VSTEP_N(HW - 8, 0);
    VSTEP_N(HW - 7, 1);
    VSTEP_N(HW - 6, 2);
    VSTEP_N(HW - 5, 3);
    VSTEP_N(HW - 4, 4);
    VSTEP_N(HW - 3, 5);
    VSTEP_N(HW - 2, 6);
    VSTEP_N(HW - 1, 7);
#undef VSTEP_L
#undef VSTEP_N
  }
}

__global__ __launch_bounds__(256) void spn_combine(
    const float4* __restrict__ w0, const float4* __restrict__ w1,
    const float4* __restrict__ w2, const float4* __restrict__ w3,
    float4* __restrict__ o) {
  const int i = blockIdx.x * 256 + threadIdx.x;
  const float4 a = w0[i], b = w1[i], c = w2[i], d = w3[i];
  float4 r;
  r.x = fmaxf(fmaxf(a.x, b.x), fmaxf(c.x, d.x));
  r.y = fmaxf(fmaxf(a.y, b.y), fmaxf(c.y, d.y));
  r.z = fmaxf(fmaxf(a.z, b.z), fmaxf(c.z, d.z));
  r.w = fmaxf(fmaxf(a.w, b.w), fmaxf(c.w, d.w));
  o[i] = r;
}

// ================= fallback path (previous passing version) =================
__global__ __launch_bounds__(256) void spn_scan_atomic(
    const float* __restrict__ x, const float* __restrict__ mask,
    unsigned* __restrict__ out) {
  const int bid = blockIdx.x;
  const int tid = threadIdx.x;
  __shared__ float tl[4][TCOLS][HW];
  __shared__ float hb[2][HW + 2];
  const size_t plane = (size_t)HW * HW;

  if (bid < 256) {
    const int dir = bid >> 7;
    const int rem = bid & 127;
    const int b = rem >> 5, ch = rem & 31;
    const bool rev = (dir == 1);
    const float* g1p = x + ((size_t)b * 12 * NF + (3 * dir + 0) * NF + ch) * plane;
    const float* g2p = x + ((size_t)b * 12 * NF + (3 * dir + 1) * NF + ch) * plane;
    const float* g3p = x + ((size_t)b * 12 * NF + (3 * dir + 2) * NF + ch) * plane;
    const float* mp  = mask + ((size_t)b * NF + ch) * plane;
    unsigned* op = out + ((size_t)b * NF + ch) * plane;

    for (int i = tid; i < 2 * (HW + 2); i += 256) (&hb[0][0])[i] = 0.0f;

    float hreg = 0.0f;
    int cur = 0;
    const int r0 = tid >> 1, cc = tid & 1;
    const float* ps[4] = {g1p, g2p, g3p, mp};
    for (int tile = 0; tile < HW / TCOLS; ++tile) {
      const int t0 = rev ? (HW - TCOLS - tile * TCOLS) : (tile * TCOLS);
      __syncthreads();
#pragma unroll
      for (int p = 0; p < 4; ++p) {
#pragma unroll
        for (int half = 0; half < 2; ++half) {
          const int r = r0 + half * 128;
          const float4 v = *(const float4*)(ps[p] + (size_t)r * HW + t0 + cc * 4);
          tl[p][cc * 4 + 0][r] = v.x;
          tl[p][cc * 4 + 1][r] = v.y;
          tl[p][cc * 4 + 2][r] = v.z;
          tl[p][cc * 4 + 3][r] = v.w;
        }
      }
      __syncthreads();
      for (int j = 0; j < TCOLS; ++j) {
        const int col = rev ? (TCOLS - 1 - j) : j;
        const int t = t0 + col;
        const float a  = tl[0][col][tid];
        const float g2 = tl[1][col][tid];
        const float c  = tl[2][col][tid];
        const float xm = tl[3][col][tid];
        const float hm = hb[cur][tid];
        const float hp = hb[cur][tid + 2];
        const float h = stepf(a, g2, c, xm, hm, hreg, hp);
        hb[cur ^ 1][tid + 1] = h;
        hreg = h;
        atomicMax(op + (size_t)tid * HW + t, enc(h));
        __syncthreads();
        cur ^= 1;
      }
    }
  } else {
    if (tid >= 64) return;
    const int lane = tid;
    const int vb = bid - 256;
    const int dir = 2 + (vb >> 7);
    const int rem = vb & 127;
    const int b = rem >> 5, ch = rem & 31;
    const bool rev = (dir == 3);
    const float* g1p = x + ((size_t)b * 12 * NF + (3 * dir + 0) * NF + ch) * plane;
    const float* g2p = x + ((size_t)b * 12 * NF + (3 * dir + 1) * NF + ch) * plane;
    const float* g3p = x + ((size_t)b * 12 * NF + (3 * dir + 2) * NF + ch) * plane;
    const float* mp  = mask + ((size_t)b * NF + ch) * plane;
    unsigned* op = out + ((size_t)b * NF + ch) * plane;

    float4 hv = {0.f, 0.f, 0.f, 0.f};
    int t = rev ? (HW - 1) : 0;
    const int koff = lane * 4;
    float4 a4 = *(const float4*)(g1p + (size_t)t * HW + koff);
    float4 b4 = *(const float4*)(g2p + (size_t)t * HW + koff);
    float4 c4 = *(const float4*)(g3p + (size_t)t * HW + koff);
    float4 x4 = *(const float4*)(mp  + (size_t)t * HW + koff);
    for (int step = 0; step < HW; ++step) {
      const float4 A = a4, B = b4, C = c4, X = x4;
      const int tn = rev ? (HW - 2 - step) : (step + 1);
      if (step + 1 < HW) {
        a4 = *(const float4*)(g1p + (size_t)tn * HW + koff);
        b4 = *(const float4*)(g2p + (size_t)tn * HW + koff);
        c4 = *(const float4*)(g3p + (size_t)tn * HW + koff);
        x4 = *(const float4*)(mp  + (size_t)tn * HW + koff);
      }
      float left = __shfl_up(hv.w, 1);
      if (lane == 0) left = 0.f;
      float right = __shfl_down(hv.x, 1);
      if (lane == 63) right = 0.f;
      float4 hn;
      hn.x = stepf(A.x, B.x, C.x, X.x, left, hv.x, hv.y);
      hn.y = stepf(A.y, B.y, C.y, X.y, hv.x, hv.y, hv.z);
      hn.z = stepf(A.z, B.z, C.z, X.z, hv.y, hv.z, hv.w);
      hn.w = stepf(A.w, B.w, C.w, X.w, hv.z, hv.w, right);
      unsigned* o = op + (size_t)t * HW + koff;
      atomicMax(o + 0, enc(hn.x));
      atomicMax(o + 1, enc(hn.y));
      atomicMax(o + 2, enc(hn.z));
      atomicMax(o + 3, enc(hn.w));
      hv = hn;
      t = tn;
    }
  }
}

__global__ __launch_bounds__(256) void spn_decode(unsigned* __restrict__ o) {
  const int i = blockIdx.x * 256 + threadIdx.x;
  uint4 v = ((uint4*)o)[i];
  float4 f;
  f.x = dec(v.x); f.y = dec(v.y); f.z = dec(v.z); f.w = dec(v.w);
  ((float4*)o)[i] = f;
}

extern "C" void kernel_launch(void* const* d_in, const int* in_sizes, int n_in,
                              void* d_out, int out_size, void* d_ws, size_t ws_size,
                              hipStream_t stream) {
  const float* x = (const float*)d_in[0];     // [4,384,256,256] f32
  const float* mask = (const float*)d_in[1];  // [4,32,256,256] f32
  (void)in_sizes; (void)n_in;
  const size_t need = (size_t)4 * out_size * sizeof(float);
  if (ws_size >= need) {
    float* ws = (float*)d_ws;
    spn_scan_ws<<<512, 64, 0, stream>>>(x, mask, ws);
    spn_combine<<<out_size / 1024, 256, 0, stream>>>(
        (const float4*)ws, (const float4*)(ws + (size_t)out_size),
        (const float4*)(ws + 2 * (size_t)out_size),
        (const float4*)(ws + 3 * (size_t)out_size), (float4*)d_out);
  } else {
    hipMemsetAsync(d_out, 0, (size_t)out_size * sizeof(float), stream);
    spn_scan_atomic<<<512, 256, 0, stream>>>(x, mask, (unsigned*)d_out);
    spn_decode<<<out_size / 1024, 256, 0, stream>>>((unsigned*)d_out);
  }
}